// Round 7
// baseline (990.616 us; speedup 1.0000x reference)
//
#include <hip/hip_runtime.h>
#include <hip/hip_bf16.h>
#include <math.h>

// Problem constants
#define NNODES 200000
#define NGRAPH 100
#define HD     128      // H == NF == 128
#define NCH    3        // virtual channels
#define BN     64       // nodes per block
#define ESTR   136      // row stride 272B: 16B-aligned (ds_read_b128), 2-way banks (free)

// r7 structure: CHANNEL-SPLIT. e_buf holds ONE channel's 64 rows (E1 then M,
// in place). Channels processed sequentially; GEMM1 acc persists across the
// loop. Wave w owns rows 16w..16w+15 -> the whole per-channel chain
// ep1->GEMM2->ep2->GEMM3->ep3 is wave-private (no barriers, fast path).
// LDS ~21.7 KB -> 4+ blocks/CU (VGPR-limited at launch_bounds(256,4)).

typedef short short8 __attribute__((ext_vector_type(8)));
typedef float f32x4  __attribute__((ext_vector_type(4)));

#define MFMA_16x16x32(a,b,c) __builtin_amdgcn_mfma_f32_16x16x32_bf16((a),(b),(c),0,0,0)

__device__ __forceinline__ float bf2f(unsigned short u) {
    return __uint_as_float(((unsigned int)u) << 16);
}
// round-half-up: 2 VALU ops; ties measure-zero for arithmetic-derived floats.
__device__ __forceinline__ unsigned short f2bf(float f) {
    return (unsigned short)((__float_as_uint(f) + 0x8000u) >> 16);
}
__device__ __forceinline__ float silu_f(float x) {
    return x * __builtin_amdgcn_rcpf(1.0f + __expf(-x));
}

// ---------------------------------------------------------------------------
// prep: blocks [0,192) repack We1[0:128]/We2/Wc1 into bf16 MFMA B-frag order
//   rep[((ct*4+ks)*64 + lane)*8 + j] = bf16(W[ks*32+(lane>>4)*8+j][ct*16+(lane&15)])
// blocks [192,492) compute Q[b,c,h] = sum_k vnf[b,k,c]*We1[128+k,h]
// ---------------------------------------------------------------------------
__global__ void prep_kernel(const float* __restrict__ We1,
                            const float* __restrict__ We2,
                            const float* __restrict__ Wc1,
                            const float* __restrict__ be1,
                            const float* __restrict__ be2,
                            const float* __restrict__ bc1,
                            const float* __restrict__ Wc2,
                            const float* __restrict__ vnf,
                            unsigned short* __restrict__ w1r,
                            unsigned short* __restrict__ w2r,
                            unsigned short* __restrict__ wc1r,
                            float* __restrict__ Q,
                            float* __restrict__ wlast,
                            float* __restrict__ be1f,
                            float* __restrict__ be2f,
                            float* __restrict__ bc1f,
                            float* __restrict__ wc2f) {
    int bid = blockIdx.x;
    if (bid < 192) {
        int t = bid * 256 + threadIdx.x;   // < 49152 = 3*16384
        int m  = t / 16384;
        int e  = t % 16384;
        int j  = e & 7;
        int l  = (e >> 3) & 63;
        int ks = (e >> 9) & 3;
        int ct = e >> 11;
        int row = ks * 32 + (l >> 4) * 8 + j;
        int col = ct * 16 + (l & 15);
        const float*    src = (m == 0) ? We1 : ((m == 1) ? We2 : Wc1);
        unsigned short* dst = (m == 0) ? w1r : ((m == 1) ? w2r : wc1r);
        dst[e] = f2bf(src[row * 128 + col]);
        if (t < 128) {
            wlast[t] = We1[256 * 128 + t];
            be1f[t]  = be1[t];
            be2f[t]  = be2[t];
            bc1f[t]  = bc1[t];
            wc2f[t]  = Wc2[t];
        }
    } else {
        int bc = bid - 192;                // 0..299
        int b = bc / NCH, c = bc % NCH;
        int t = threadIdx.x;
        __shared__ float v[128];
        if (t < 128) v[t] = vnf[(b * 128 + t) * 3 + c];
        __syncthreads();
        if (t < 128) {
            float s = 0.0f;
            for (int k = 0; k < 128; ++k)
                s += v[k] * We1[(128 + k) * 128 + t];
            Q[(b * 3 + c) * 128 + t] = s;
        }
    }
}

// ---------------------------------------------------------------------------
// Main fused kernel: 64 nodes/block, 256 threads (4 waves), 3125 blocks.
// ---------------------------------------------------------------------------
__global__ __launch_bounds__(256, 4) void egcl_main(
    const float* __restrict__ node_feat,   // [N,128]
    const float* __restrict__ coord,       // [N,3]
    const float* __restrict__ vcoord,      // [B,3,C]
    const int*   __restrict__ batch,       // [N] sorted
    const unsigned short* __restrict__ w1r,
    const unsigned short* __restrict__ w2r,
    const unsigned short* __restrict__ wc1r,
    const float* __restrict__ Q,           // [B,C,H]
    const float* __restrict__ wlast,
    const float* __restrict__ be1f,
    const float* __restrict__ be2f,
    const float* __restrict__ bc1f,
    const float* __restrict__ wc2f,
    float* __restrict__ aggsum,            // [B,C,H]
    float* __restrict__ transsum,          // [B,3,C]
    float* __restrict__ cnt)               // [B]
{
    __shared__ __align__(16) unsigned short e_buf[BN * ESTR]; // 17408 B (1 channel)
    __shared__ __align__(16) f32x4 sdr[NCH][BN];   // 3072 B: dx,dy,dz,radial fp32
    __shared__ float s_s[NCH * BN];                // 768 B: s per (channel,node)
    __shared__ unsigned short sbatch[BN];
    __shared__ unsigned short sseg_start[BN + 1];
    __shared__ unsigned short sseg_b[BN];
    __shared__ int snseg;

    const int tid   = threadIdx.x;
    const int wave  = tid >> 6;
    const int lane  = tid & 63;
    const int lrow  = lane & 15;           // MFMA row (A) / col (D) index
    const int lkb   = (lane >> 4) * 8;     // k-offset base within 32-wide K step
    const int rq    = (lane >> 4) * 4;     // D row-group base
    const int node0 = blockIdx.x * BN;

    // ---- Phase 0 ----
    if (tid < BN) {  // wave 0
        int n = node0 + tid;
        int b = batch[n];
        sbatch[tid] = (unsigned short)b;
        int prev = (tid > 0) ? batch[n - 1] : -1;
        unsigned long long mask = __ballot(b != prev);
        int ns = __popcll(mask);
        if (b != prev) {
            int idx = __popcll(mask & ((1ull << tid) - 1ull));
            sseg_start[idx] = (unsigned short)tid;
            sseg_b[idx]     = (unsigned short)b;
        }
        if (tid == 0) { sseg_start[ns] = BN; snseg = ns; }
        float cx = coord[n * 3 + 0];
        float cy = coord[n * 3 + 1];
        float cz = coord[n * 3 + 2];
        for (int c = 0; c < 3; ++c) {
            f32x4 pad;
            pad[0] = vcoord[b * 9 + 0 * 3 + c] - cx;
            pad[1] = vcoord[b * 9 + 1 * 3 + c] - cy;
            pad[2] = vcoord[b * 9 + 2 * 3 + c] - cz;
            pad[3] = sqrtf(pad[0]*pad[0] + pad[1]*pad[1] + pad[2]*pad[2]);
            sdr[c][tid] = pad;
        }
    }
    __syncthreads();
    const int nseg = snseg;   // block-uniform

    // ---- GEMM1: P[64,128] = node_feat_tile @ We1_top; wave w -> nodes 16w..16w+15
    f32x4 acc1[8] = {};      // persists across the channel loop
    {
        const float* arow = node_feat + (size_t)(node0 + wave * 16 + lrow) * 128;
        for (int ks = 0; ks < 4; ++ks) {
            f32x4 x0 = *(const f32x4*)(arow + ks * 32 + lkb);
            f32x4 x1 = *(const f32x4*)(arow + ks * 32 + lkb + 4);
            short8 af;
            af[0] = (short)f2bf(x0[0]); af[1] = (short)f2bf(x0[1]);
            af[2] = (short)f2bf(x0[2]); af[3] = (short)f2bf(x0[3]);
            af[4] = (short)f2bf(x1[0]); af[5] = (short)f2bf(x1[1]);
            af[6] = (short)f2bf(x1[2]); af[7] = (short)f2bf(x1[3]);
            for (int ct = 0; ct < 8; ++ct) {
                short8 bfg = *(const short8*)(w1r + ((ct * 4 + ks) * 64 + lane) * 8);
                acc1[ct] = MFMA_16x16x32(af, bfg, acc1[ct]);
            }
        }
    }

    float wl[8], bb1[8];
    #pragma unroll
    for (int ct = 0; ct < 8; ++ct) {
        wl[ct]  = wlast[ct * 16 + lrow];
        bb1[ct] = be1f[ct * 16 + lrow];
    }
    const int b0   = (int)sseg_b[0];
    const int bagg = b0 * (NCH * HD);

    // ---- Channel loop ----
    for (int c = 0; c < 3; ++c) {
        // Epilogue 1_c: E1[nl,h] = silu(P + Q[b,c,h] + radial*wlast + be1)
        if (nseg == 1) {
            const float* qb = Q + bagg + c * 128;
            float qv[8];
            #pragma unroll
            for (int ct = 0; ct < 8; ++ct) qv[ct] = qb[ct * 16 + lrow];
            #pragma unroll
            for (int r = 0; r < 4; ++r) {
                int nl = wave * 16 + rq + r;
                float rad = sdr[c][nl][3];
                #pragma unroll
                for (int ct = 0; ct < 8; ++ct) {
                    float x = acc1[ct][r] + bb1[ct] + qv[ct] + rad * wl[ct];
                    e_buf[nl * ESTR + ct * 16 + lrow] = f2bf(silu_f(x));
                }
            }
        } else {
            #pragma unroll
            for (int r = 0; r < 4; ++r) {
                int nl = wave * 16 + rq + r;
                int b  = sbatch[nl];
                float rad = sdr[c][nl][3];
                const float* qb = Q + (b * 3 + c) * 128;
                #pragma unroll
                for (int ct = 0; ct < 8; ++ct) {
                    float x = acc1[ct][r] + bb1[ct] + qb[ct * 16 + lrow] + rad * wl[ct];
                    e_buf[nl * ESTR + ct * 16 + lrow] = f2bf(silu_f(x));
                }
            }
        }
        // (no barrier: rows 16w..16w+15 are wave-private)

        // GEMM2_c: M = silu(E1 @ We2 + be2)
        {
            f32x4 acc[8] = {};
            for (int ks = 0; ks < 4; ++ks) {
                short8 af = *(const short8*)(&e_buf[(wave * 16 + lrow) * ESTR +
                                                    ks * 32 + lkb]);
                for (int ct = 0; ct < 8; ++ct) {
                    short8 bfg = *(const short8*)(w2r + ((ct * 4 + ks) * 64 + lane) * 8);
                    acc[ct] = MFMA_16x16x32(af, bfg, acc[ct]);
                }
            }
            // Epilogue 2_c: write M (bf16) + fast-path segment-sum to global
            for (int ct = 0; ct < 8; ++ct) {
                int h = ct * 16 + lrow;
                float bb = be2f[h];
                float psum = 0.0f;
                #pragma unroll
                for (int r = 0; r < 4; ++r) {
                    int row = wave * 16 + rq + r;
                    float v = silu_f(acc[ct][r] + bb);
                    e_buf[row * ESTR + h] = f2bf(v);
                    psum += v;
                }
                if (nseg == 1) {
                    psum += __shfl_xor(psum, 16, 64);
                    psum += __shfl_xor(psum, 32, 64);
                    if (lane < 16)
                        atomicAdd(&aggsum[bagg + c * 128 + ct * 16 + lane], psum);
                }
            }
        }

        // Slow-path aggsum (3% of blocks): needs all waves' M rows
        if (nseg > 1) {
            __syncthreads();
            for (int sg = 0; sg < nseg; ++sg) {
                int s0 = sseg_start[sg], s1 = sseg_start[sg + 1], b = sseg_b[sg];
                for (int h = tid; h < HD; h += 256) {
                    float sum = 0.f;
                    for (int ii = s0; ii < s1; ++ii)
                        sum += bf2f(e_buf[ii * ESTR + h]);
                    atomicAdd(&aggsum[(b * 3 + c) * 128 + h], sum);
                }
            }
        }

        // GEMM3_c: SH = silu(M @ Wc1 + bc1); s = SH . Wc2 (never materialized)
        {
            f32x4 acc[8] = {};
            for (int ks = 0; ks < 4; ++ks) {
                short8 af = *(const short8*)(&e_buf[(wave * 16 + lrow) * ESTR +
                                                    ks * 32 + lkb]);
                for (int ct = 0; ct < 8; ++ct) {
                    short8 bfg = *(const short8*)(wc1r + ((ct * 4 + ks) * 64 + lane) * 8);
                    acc[ct] = MFMA_16x16x32(af, bfg, acc[ct]);
                }
            }
            float p0 = 0.f, p1 = 0.f, p2 = 0.f, p3 = 0.f;
            for (int ct = 0; ct < 8; ++ct) {
                int h = ct * 16 + lrow;
                float bb = bc1f[h];
                float w2 = wc2f[h];
                p0 += silu_f(acc[ct][0] + bb) * w2;
                p1 += silu_f(acc[ct][1] + bb) * w2;
                p2 += silu_f(acc[ct][2] + bb) * w2;
                p3 += silu_f(acc[ct][3] + bb) * w2;
            }
            #pragma unroll
            for (int off = 1; off < 16; off <<= 1) {
                p0 += __shfl_xor(p0, off, 64);
                p1 += __shfl_xor(p1, off, 64);
                p2 += __shfl_xor(p2, off, 64);
                p3 += __shfl_xor(p3, off, 64);
            }
            if (lrow == 0) {
                int rbase = c * 64 + wave * 16 + rq;
                s_s[rbase + 0] = p0;
                s_s[rbase + 1] = p1;
                s_s[rbase + 2] = p2;
                s_s[rbase + 3] = p3;
            }
        }

        // protect e_buf from next channel's ep1 while slow-path readers finish
        if (nseg > 1) __syncthreads();
    }
    __syncthreads();

    // ---- Trans reduce + cnt ----
    if (nseg == 1) {
        if (wave == 0) {   // 64-lane shuffle tree over nodes
            float t[9];
            #pragma unroll
            for (int c = 0; c < 3; ++c) {
                float sv = s_s[c * 64 + lane];
                f32x4 d  = sdr[c][lane];
                t[0 * 3 + c] = d[0] * sv;
                t[1 * 3 + c] = d[1] * sv;
                t[2 * 3 + c] = d[2] * sv;
            }
            #pragma unroll
            for (int off = 1; off < 64; off <<= 1)
                #pragma unroll
                for (int k = 0; k < 9; ++k)
                    t[k] += __shfl_xor(t[k], off, 64);
            if (lane == 0) {
                #pragma unroll
                for (int k = 0; k < 9; ++k)
                    atomicAdd(&transsum[b0 * 9 + k], t[k]);
                atomicAdd(&cnt[b0], 64.0f);
            }
        }
    } else {
        for (int sg = 0; sg < nseg; ++sg) {
            int s0 = sseg_start[sg], s1 = sseg_start[sg + 1], b = sseg_b[sg];
            if (tid < 9) {
                int d = tid / 3, c = tid % 3;
                float sum = 0.f;
                for (int ii = s0; ii < s1; ++ii)
                    sum += sdr[c][ii][d] * s_s[c * 64 + ii];
                atomicAdd(&transsum[b * 9 + d * 3 + c], sum);
            }
            if (tid == 0) atomicAdd(&cnt[b], (float)(s1 - s0));
        }
    }
}

// ---------------------------------------------------------------------------
// Finalize: one block per (b,c) row. Means, node model, residuals, outputs.
// ---------------------------------------------------------------------------
__global__ void finalize_kernel(const float* __restrict__ vnf,
                                const float* __restrict__ vcoord,
                                const float* __restrict__ Wn1,
                                const float* __restrict__ bn1,
                                const float* __restrict__ Wn2,
                                const float* __restrict__ bn2,
                                const float* __restrict__ aggsum,
                                const float* __restrict__ transsum,
                                const float* __restrict__ cnt,
                                float* __restrict__ out) {
    int b = blockIdx.x / NCH;
    int c = blockIdx.x % NCH;
    int j = threadIdx.x;   // 0..127
    __shared__ float nin[256];
    __shared__ float h1[128];
    float count = fmaxf(cnt[b], 1.0f);
    nin[j]       = vnf[(b * 128 + j) * 3 + c];
    nin[128 + j] = aggsum[(b * 3 + c) * 128 + j] / count;
    __syncthreads();
    float x = bn1[j];
    for (int k = 0; k < 256; ++k)
        x += nin[k] * Wn1[k * 128 + j];
    h1[j] = silu_f(x);
    __syncthreads();
    float y = bn2[j];
    for (int k = 0; k < 128; ++k)
        y += h1[k] * Wn2[k * 128 + j];
    out[(b * 128 + j) * 3 + c] = vnf[(b * 128 + j) * 3 + c] + y;
    if (c == 0 && j < 9) {
        out[NGRAPH * 128 * 3 + b * 9 + j] =
            vcoord[b * 9 + j] + transsum[b * 9 + j] / count;
    }
}

// ---------------------------------------------------------------------------
extern "C" void kernel_launch(void* const* d_in, const int* in_sizes, int n_in,
                              void* d_out, int out_size, void* d_ws, size_t ws_size,
                              hipStream_t stream) {
    const float* node_feat = (const float*)d_in[0];
    const float* coord     = (const float*)d_in[1];
    const float* vnf       = (const float*)d_in[2];
    const float* vcoord    = (const float*)d_in[3];
    const int*   batch     = (const int*)d_in[4];
    const float* We1 = (const float*)d_in[5];
    const float* be1 = (const float*)d_in[6];
    const float* We2 = (const float*)d_in[7];
    const float* be2 = (const float*)d_in[8];
    const float* Wc1 = (const float*)d_in[9];
    const float* bc1 = (const float*)d_in[10];
    const float* Wc2 = (const float*)d_in[11];
    const float* Wn1 = (const float*)d_in[12];
    const float* bn1 = (const float*)d_in[13];
    const float* Wn2 = (const float*)d_in[14];
    const float* bn2 = (const float*)d_in[15];

    char* ws = (char*)d_ws;
    float*          aggsum   = (float*)(ws + 0);          // 153600
    float*          transsum = (float*)(ws + 153600);     // 3600
    float*          cntp     = (float*)(ws + 157200);     // 400
    float*          Q        = (float*)(ws + 157600);     // 153600
    unsigned short* w1r      = (unsigned short*)(ws + 311200); // 32768
    unsigned short* w2r      = (unsigned short*)(ws + 343968); // 32768
    unsigned short* wc1r     = (unsigned short*)(ws + 376736); // 32768
    float*          wlast    = (float*)(ws + 409504);
    float*          be1f     = (float*)(ws + 410016);
    float*          be2f     = (float*)(ws + 410528);
    float*          bc1f     = (float*)(ws + 411040);
    float*          wc2f     = (float*)(ws + 411552);

    (void)hipMemsetAsync(d_ws, 0, 157600, stream);  // zero accumulators each call

    prep_kernel<<<192 + NGRAPH * NCH, 256, 0, stream>>>(
        We1, We2, Wc1, be1, be2, bc1, Wc2, vnf,
        w1r, w2r, wc1r, Q, wlast, be1f, be2f, bc1f, wc2f);

    egcl_main<<<NNODES / BN, 256, 0, stream>>>(
        node_feat, coord, vcoord, batch, w1r, w2r, wc1r, Q,
        wlast, be1f, be2f, bc1f, wc2f, aggsum, transsum, cntp);

    finalize_kernel<<<NGRAPH * NCH, 128, 0, stream>>>(
        vnf, vcoord, Wn1, bn1, Wn2, bn2, aggsum, transsum, cntp,
        (float*)d_out);
}

// Round 8
// 345.222 us; speedup vs baseline: 2.8695x; 2.8695x over previous
//
#include <hip/hip_runtime.h>
#include <hip/hip_bf16.h>
#include <math.h>

// Problem constants
#define NNODES 200000
#define NGRAPH 100
#define HD     128      // H == NF == 128
#define NCH    3        // virtual channels
#define BN     64      // nodes per block
#define EROWS  (BN*NCH) // 192 e-rows per block
#define ESTR   136      // 128 data + 8 pad cols; row stride 272B (16B aligned)
// Pad cols per row (row' = c*64+nl): [128..129]=fp32 dx, [130..131]=fp32 dy,
// [132..133]=fp32 dz, [134..135]=fp32 radial  (exact fp32, 16B aligned block).
// e_buf row layout: row' = c*64 + nl (channel-major) -> every 16-row MFMA chunk
// is channel-pure; wave w owns chunks {w, w+4, w+8} = rows its epilogue-1 wrote
// -> GEMM1->2->3 need NO barriers.
//
// r8: GEMM2/GEMM3 split into two ct-halves (acc[3][4] = 48 AGPR live instead
// of 96) so peak combined VGPR+AGPR ~152 <= 170 -> 3 blocks/CU resident at the
// full 256-reg budget. launch_bounds stays (256,2): it's a floor (budget),
// not a cap; occupancy comes from actual usage. (r3/r4/r7 lesson: any budget
// <256 makes the allocator split the file and spill ~GBs of scratch.)

typedef short short8 __attribute__((ext_vector_type(8)));
typedef float f32x4  __attribute__((ext_vector_type(4)));

#define MFMA_16x16x32(a,b,c) __builtin_amdgcn_mfma_f32_16x16x32_bf16((a),(b),(c),0,0,0)

__device__ __forceinline__ float bf2f(unsigned short u) {
    return __uint_as_float(((unsigned int)u) << 16);
}
// round-half-up: 2 VALU ops; ties measure-zero for arithmetic-derived floats.
__device__ __forceinline__ unsigned short f2bf(float f) {
    return (unsigned short)((__float_as_uint(f) + 0x8000u) >> 16);
}
__device__ __forceinline__ float silu_f(float x) {
    return x * __builtin_amdgcn_rcpf(1.0f + __expf(-x));
}

// ---------------------------------------------------------------------------
// prep: blocks [0,192) repack We1[0:128]/We2/Wc1 into bf16 MFMA B-frag order
//   rep[((ct*4+ks)*64 + lane)*8 + j] = bf16(W[ks*32+(lane>>4)*8+j][ct*16+(lane&15)])
// blocks [192,492) compute Q[b,c,h] = sum_k vnf[b,k,c]*We1[128+k,h]
// ---------------------------------------------------------------------------
__global__ void prep_kernel(const float* __restrict__ We1,
                            const float* __restrict__ We2,
                            const float* __restrict__ Wc1,
                            const float* __restrict__ be1,
                            const float* __restrict__ be2,
                            const float* __restrict__ bc1,
                            const float* __restrict__ Wc2,
                            const float* __restrict__ vnf,
                            unsigned short* __restrict__ w1r,
                            unsigned short* __restrict__ w2r,
                            unsigned short* __restrict__ wc1r,
                            float* __restrict__ Q,
                            float* __restrict__ wlast,
                            float* __restrict__ be1f,
                            float* __restrict__ be2f,
                            float* __restrict__ bc1f,
                            float* __restrict__ wc2f) {
    int bid = blockIdx.x;
    if (bid < 192) {
        int t = bid * 256 + threadIdx.x;   // < 49152 = 3*16384
        int m  = t / 16384;
        int e  = t % 16384;
        int j  = e & 7;
        int l  = (e >> 3) & 63;
        int ks = (e >> 9) & 3;
        int ct = e >> 11;
        int row = ks * 32 + (l >> 4) * 8 + j;
        int col = ct * 16 + (l & 15);
        const float*    src = (m == 0) ? We1 : ((m == 1) ? We2 : Wc1);
        unsigned short* dst = (m == 0) ? w1r : ((m == 1) ? w2r : wc1r);
        dst[e] = f2bf(src[row * 128 + col]);
        if (t < 128) {
            wlast[t] = We1[256 * 128 + t];
            be1f[t]  = be1[t];
            be2f[t]  = be2[t];
            bc1f[t]  = bc1[t];
            wc2f[t]  = Wc2[t];
        }
    } else {
        int bc = bid - 192;                // 0..299
        int b = bc / NCH, c = bc % NCH;
        int t = threadIdx.x;
        __shared__ float v[128];
        if (t < 128) v[t] = vnf[(b * 128 + t) * 3 + c];
        __syncthreads();
        if (t < 128) {
            float s = 0.0f;
            for (int k = 0; k < 128; ++k)
                s += v[k] * We1[(128 + k) * 128 + t];
            Q[(b * 3 + c) * 128 + t] = s;
        }
    }
}

// ---------------------------------------------------------------------------
// Main fused kernel: 64 nodes/block, 256 threads (4 waves), 3125 blocks.
// ---------------------------------------------------------------------------
__global__ __launch_bounds__(256, 2) void egcl_main(
    const float* __restrict__ node_feat,   // [N,128]
    const float* __restrict__ coord,       // [N,3]
    const float* __restrict__ vcoord,      // [B,3,C]
    const int*   __restrict__ batch,       // [N] sorted
    const unsigned short* __restrict__ w1r,
    const unsigned short* __restrict__ w2r,
    const unsigned short* __restrict__ wc1r,
    const float* __restrict__ Q,           // [B,C,H]
    const float* __restrict__ wlast,
    const float* __restrict__ be1f,
    const float* __restrict__ be2f,
    const float* __restrict__ bc1f,
    const float* __restrict__ wc2f,
    float* __restrict__ aggsum,            // [B,C,H]
    float* __restrict__ transsum,          // [B,3,C]
    float* __restrict__ cnt)               // [B]
{
    __shared__ __align__(16) unsigned short e_buf[EROWS * ESTR]; // 52224 B
    __shared__ float s_s[EROWS];            // 768 B (indexed by row' = c*64+nl)
    __shared__ unsigned short sbatch[BN];
    __shared__ unsigned short sseg_start[BN + 1];
    __shared__ unsigned short sseg_b[BN];
    __shared__ int snseg;

    const int tid   = threadIdx.x;
    const int wave  = tid >> 6;
    const int lane  = tid & 63;
    const int lrow  = lane & 15;           // MFMA row (A) / col (D) index
    const int lkb   = (lane >> 4) * 8;     // k-offset base within 32-wide K step
    const int rq    = (lane >> 4) * 4;     // D row-group base
    const int node0 = blockIdx.x * BN;

    // ---- Phase 0 ----
    if (tid < BN) {  // wave 0
        int n = node0 + tid;
        int b = batch[n];
        sbatch[tid] = (unsigned short)b;
        int prev = (tid > 0) ? batch[n - 1] : -1;
        unsigned long long mask = __ballot(b != prev);
        int ns = __popcll(mask);
        if (b != prev) {
            int idx = __popcll(mask & ((1ull << tid) - 1ull));
            sseg_start[idx] = (unsigned short)tid;
            sseg_b[idx]     = (unsigned short)b;
        }
        if (tid == 0) { sseg_start[ns] = BN; snseg = ns; }
        float cx = coord[n * 3 + 0];
        float cy = coord[n * 3 + 1];
        float cz = coord[n * 3 + 2];
        for (int c = 0; c < 3; ++c) {
            float dx = vcoord[b * 9 + 0 * 3 + c] - cx;
            float dy = vcoord[b * 9 + 1 * 3 + c] - cy;
            float dz = vcoord[b * 9 + 2 * 3 + c] - cz;
            f32x4 pad;
            pad[0] = dx; pad[1] = dy; pad[2] = dz;
            pad[3] = sqrtf(dx * dx + dy * dy + dz * dz);
            *(f32x4*)&e_buf[(c * 64 + tid) * ESTR + 128] = pad;  // 16B aligned
        }
    }
    __syncthreads();
    const int nseg = snseg;   // block-uniform

    // ---- GEMM1: P[64,128] = node_feat_tile @ We1_top; wave w -> nodes 16w..16w+15
    f32x4 acc1[8] = {};
    {
        const float* arow = node_feat + (size_t)(node0 + wave * 16 + lrow) * 128;
        for (int ks = 0; ks < 4; ++ks) {
            f32x4 x0 = *(const f32x4*)(arow + ks * 32 + lkb);
            f32x4 x1 = *(const f32x4*)(arow + ks * 32 + lkb + 4);
            short8 af;
            af[0] = (short)f2bf(x0[0]); af[1] = (short)f2bf(x0[1]);
            af[2] = (short)f2bf(x0[2]); af[3] = (short)f2bf(x0[3]);
            af[4] = (short)f2bf(x1[0]); af[5] = (short)f2bf(x1[1]);
            af[6] = (short)f2bf(x1[2]); af[7] = (short)f2bf(x1[3]);
            for (int ct = 0; ct < 8; ++ct) {
                short8 bfg = *(const short8*)(w1r + ((ct * 4 + ks) * 64 + lane) * 8);
                acc1[ct] = MFMA_16x16x32(af, bfg, acc1[ct]);
            }
        }
    }
    // Epilogue 1: E1[c*64+nl, h] = silu(P + Q[b,c,h] + radial*wlast[h] + be1[h])
    {
        float wl[8], bb[8];
        #pragma unroll
        for (int ct = 0; ct < 8; ++ct) {
            wl[ct] = wlast[ct * 16 + lrow];
            bb[ct] = be1f[ct * 16 + lrow];
        }
        if (nseg == 1) {
            const float* qb = Q + (int)sseg_b[0] * (NCH * HD);
            float qv[3][8];
            #pragma unroll
            for (int c = 0; c < 3; ++c)
                #pragma unroll
                for (int ct = 0; ct < 8; ++ct)
                    qv[c][ct] = qb[c * 128 + ct * 16 + lrow] + bb[ct];
            #pragma unroll
            for (int r = 0; r < 4; ++r) {
                int nl = wave * 16 + rq + r;
                #pragma unroll
                for (int c = 0; c < 3; ++c) {
                    int row = c * 64 + nl;
                    float rad = *(const float*)&e_buf[row * ESTR + 134];
                    #pragma unroll
                    for (int ct = 0; ct < 8; ++ct) {
                        float x = acc1[ct][r] + qv[c][ct] + rad * wl[ct];
                        e_buf[row * ESTR + ct * 16 + lrow] = f2bf(silu_f(x));
                    }
                }
            }
        } else {
            #pragma unroll
            for (int r = 0; r < 4; ++r) {
                int nl = wave * 16 + rq + r;
                int b  = sbatch[nl];
                #pragma unroll
                for (int c = 0; c < 3; ++c) {
                    int row = c * 64 + nl;
                    float rad = *(const float*)&e_buf[row * ESTR + 134];
                    const float* qb = Q + (b * 3 + c) * 128;
                    #pragma unroll
                    for (int ct = 0; ct < 8; ++ct) {
                        float x = acc1[ct][r] + bb[ct] + qb[ct * 16 + lrow] + rad * wl[ct];
                        e_buf[row * ESTR + ct * 16 + lrow] = f2bf(silu_f(x));
                    }
                }
            }
        }
    }
    // (no barrier: wave w's chunks {w, w+4, w+8} are exactly the rows it wrote)

    const int bagg = (nseg == 1) ? (int)sseg_b[0] * (NCH * HD) : 0;

    // ---- GEMM2: M = silu(E1 @ We2 + be2), in two ct-halves (48 AGPR live) ----
    for (int half = 0; half < 2; ++half) {
        f32x4 acc[3][4] = {};
        for (int ks = 0; ks < 4; ++ks) {
            short8 af[3];
            #pragma unroll
            for (int j = 0; j < 3; ++j)
                af[j] = *(const short8*)(&e_buf[(j * 64 + wave * 16 + lrow) * ESTR +
                                                ks * 32 + lkb]);
            #pragma unroll
            for (int c4 = 0; c4 < 4; ++c4) {
                int ct = half * 4 + c4;
                short8 bfg = *(const short8*)(w2r + ((ct * 4 + ks) * 64 + lane) * 8);
                #pragma unroll
                for (int j = 0; j < 3; ++j)
                    acc[j][c4] = MFMA_16x16x32(af[j], bfg, acc[j][c4]);
            }
        }
        // Epilogue 2 (this half): write M (bf16) + fast-path segment-sum
        for (int j = 0; j < 3; ++j) {
            #pragma unroll
            for (int c4 = 0; c4 < 4; ++c4) {
                int ct = half * 4 + c4;
                int h = ct * 16 + lrow;
                float bb = be2f[h];
                float psum = 0.0f;
                #pragma unroll
                for (int r = 0; r < 4; ++r) {
                    int row = j * 64 + wave * 16 + rq + r;
                    float v = silu_f(acc[j][c4][r] + bb);
                    e_buf[row * ESTR + h] = f2bf(v);
                    psum += v;
                }
                if (nseg == 1) {
                    psum += __shfl_xor(psum, 16, 64);
                    psum += __shfl_xor(psum, 32, 64);
                    if (lane < 16)
                        atomicAdd(&aggsum[bagg + j * 128 + ct * 16 + lane], psum);
                }
            }
        }
    }

    // ---- GEMM3: SH = silu(M @ Wc1 + bc1); s = SH . Wc2, two ct-halves ----
    float p[3][4] = {};
    for (int half = 0; half < 2; ++half) {
        f32x4 acc[3][4] = {};
        for (int ks = 0; ks < 4; ++ks) {
            short8 af[3];
            #pragma unroll
            for (int j = 0; j < 3; ++j)
                af[j] = *(const short8*)(&e_buf[(j * 64 + wave * 16 + lrow) * ESTR +
                                                ks * 32 + lkb]);
            #pragma unroll
            for (int c4 = 0; c4 < 4; ++c4) {
                int ct = half * 4 + c4;
                short8 bfg = *(const short8*)(wc1r + ((ct * 4 + ks) * 64 + lane) * 8);
                #pragma unroll
                for (int j = 0; j < 3; ++j)
                    acc[j][c4] = MFMA_16x16x32(af[j], bfg, acc[j][c4]);
            }
        }
        for (int j = 0; j < 3; ++j) {
            #pragma unroll
            for (int c4 = 0; c4 < 4; ++c4) {
                int ct = half * 4 + c4;
                int h = ct * 16 + lrow;
                float bb = bc1f[h];
                float w2 = wc2f[h];
                #pragma unroll
                for (int r = 0; r < 4; ++r)
                    p[j][r] += silu_f(acc[j][c4][r] + bb) * w2;
            }
        }
    }
    for (int j = 0; j < 3; ++j) {
        float p0 = p[j][0], p1 = p[j][1], p2 = p[j][2], p3 = p[j][3];
        #pragma unroll
        for (int off = 1; off < 16; off <<= 1) {
            p0 += __shfl_xor(p0, off, 64);
            p1 += __shfl_xor(p1, off, 64);
            p2 += __shfl_xor(p2, off, 64);
            p3 += __shfl_xor(p3, off, 64);
        }
        if (lrow == 0) {
            int rbase = j * 64 + wave * 16 + rq;
            s_s[rbase + 0] = p0;
            s_s[rbase + 1] = p1;
            s_s[rbase + 2] = p2;
            s_s[rbase + 3] = p3;
        }
    }
    __syncthreads();

    // ---- Reduce to global (aggsum fast path already done in epilogue 2) ----
    if (nseg == 1) {
        int b = sseg_b[0];
        if (wave == 0) {   // trans: 64-lane shuffle tree over nodes
            float t[9];
            #pragma unroll
            for (int c = 0; c < 3; ++c) {
                int row = c * 64 + lane;
                float sv = s_s[row];
                float dx = *(const float*)&e_buf[row * ESTR + 128];
                float dy = *(const float*)&e_buf[row * ESTR + 130];
                float dz = *(const float*)&e_buf[row * ESTR + 132];
                t[0 * 3 + c] = dx * sv;
                t[1 * 3 + c] = dy * sv;
                t[2 * 3 + c] = dz * sv;
            }
            #pragma unroll
            for (int off = 1; off < 64; off <<= 1)
                #pragma unroll
                for (int k = 0; k < 9; ++k)
                    t[k] += __shfl_xor(t[k], off, 64);
            if (lane < 9)
                atomicAdd(&transsum[b * 9 + lane],
                          __shfl(t[lane], 0, 64));  // lane0 holds full sums
            if (lane == 0) atomicAdd(&cnt[b], 64.0f);
        }
    } else {
        for (int sg = 0; sg < nseg; ++sg) {
            int s0 = sseg_start[sg], s1 = sseg_start[sg + 1], b = sseg_b[sg];
            for (int idx = tid; idx < NCH * HD; idx += 256) {
                int c = idx >> 7, h = idx & 127;
                float sum = 0.f;
                for (int ii = s0; ii < s1; ++ii)
                    sum += bf2f(e_buf[(c * 64 + ii) * ESTR + h]);
                atomicAdd(&aggsum[(b * 3 + c) * 128 + h], sum);
            }
            if (tid < 9) {
                int d = tid / 3, c = tid % 3;
                float sum = 0.f;
                for (int ii = s0; ii < s1; ++ii)
                    sum += (*(const float*)&e_buf[(c * 64 + ii) * ESTR + 128 + 2 * d])
                           * s_s[c * 64 + ii];
                atomicAdd(&transsum[b * 9 + d * 3 + c], sum);
            }
            if (tid == 0) atomicAdd(&cnt[b], (float)(s1 - s0));
        }
    }
}

// ---------------------------------------------------------------------------
// Finalize: one block per (b,c) row. Means, node model, residuals, outputs.
// ---------------------------------------------------------------------------
__global__ void finalize_kernel(const float* __restrict__ vnf,
                                const float* __restrict__ vcoord,
                                const float* __restrict__ Wn1,
                                const float* __restrict__ bn1,
                                const float* __restrict__ Wn2,
                                const float* __restrict__ bn2,
                                const float* __restrict__ aggsum,
                                const float* __restrict__ transsum,
                                const float* __restrict__ cnt,
                                float* __restrict__ out) {
    int b = blockIdx.x / NCH;
    int c = blockIdx.x % NCH;
    int j = threadIdx.x;   // 0..127
    __shared__ float nin[256];
    __shared__ float h1[128];
    float count = fmaxf(cnt[b], 1.0f);
    nin[j]       = vnf[(b * 128 + j) * 3 + c];
    nin[128 + j] = aggsum[(b * 3 + c) * 128 + j] / count;
    __syncthreads();
    float x = bn1[j];
    for (int k = 0; k < 256; ++k)
        x += nin[k] * Wn1[k * 128 + j];
    h1[j] = silu_f(x);
    __syncthreads();
    float y = bn2[j];
    for (int k = 0; k < 128; ++k)
        y += h1[k] * Wn2[k * 128 + j];
    out[(b * 128 + j) * 3 + c] = vnf[(b * 128 + j) * 3 + c] + y;
    if (c == 0 && j < 9) {
        out[NGRAPH * 128 * 3 + b * 9 + j] =
            vcoord[b * 9 + j] + transsum[b * 9 + j] / count;
    }
}

// ---------------------------------------------------------------------------
extern "C" void kernel_launch(void* const* d_in, const int* in_sizes, int n_in,
                              void* d_out, int out_size, void* d_ws, size_t ws_size,
                              hipStream_t stream) {
    const float* node_feat = (const float*)d_in[0];
    const float* coord     = (const float*)d_in[1];
    const float* vnf       = (const float*)d_in[2];
    const float* vcoord    = (const float*)d_in[3];
    const int*   batch     = (const int*)d_in[4];
    const float* We1 = (const float*)d_in[5];
    const float* be1 = (const float*)d_in[6];
    const float* We2 = (const float*)d_in[7];
    const float* be2 = (const float*)d_in[8];
    const float* Wc1 = (const float*)d_in[9];
    const float* bc1 = (const float*)d_in[10];
    const float* Wc2 = (const float*)d_in[11];
    const float* Wn1 = (const float*)d_in[12];
    const float* bn1 = (const float*)d_in[13];
    const float* Wn2 = (const float*)d_in[14];
    const float* bn2 = (const float*)d_in[15];

    char* ws = (char*)d_ws;
    float*          aggsum   = (float*)(ws + 0);          // 153600
    float*          transsum = (float*)(ws + 153600);     // 3600
    float*          cntp     = (float*)(ws + 157200);     // 400
    float*          Q        = (float*)(ws + 157600);     // 153600
    unsigned short* w1r      = (unsigned short*)(ws + 311200); // 32768
    unsigned short* w2r      = (unsigned short*)(ws + 343968); // 32768
    unsigned short* wc1r     = (unsigned short*)(ws + 376736); // 32768
    float*          wlast    = (float*)(ws + 409504);
    float*          be1f     = (float*)(ws + 410016);
    float*          be2f     = (float*)(ws + 410528);
    float*          bc1f     = (float*)(ws + 411040);
    float*          wc2f     = (float*)(ws + 411552);

    (void)hipMemsetAsync(d_ws, 0, 157600, stream);  // zero accumulators each call

    prep_kernel<<<192 + NGRAPH * NCH, 256, 0, stream>>>(
        We1, We2, Wc1, be1, be2, bc1, Wc2, vnf,
        w1r, w2r, wc1r, Q, wlast, be1f, be2f, bc1f, wc2f);

    egcl_main<<<NNODES / BN, 256, 0, stream>>>(
        node_feat, coord, vcoord, batch, w1r, w2r, wc1r, Q,
        wlast, be1f, be2f, bc1f, wc2f, aggsum, transsum, cntp);

    finalize_kernel<<<NGRAPH * NCH, 128, 0, stream>>>(
        vnf, vcoord, Wn1, bn1, Wn2, bn2, aggsum, transsum, cntp,
        (float*)d_out);
}

// Round 9
// 324.194 us; speedup vs baseline: 3.0556x; 1.0649x over previous
//
#include <hip/hip_runtime.h>
#include <hip/hip_bf16.h>
#include <math.h>

// Problem constants
#define NNODES 200000
#define NGRAPH 100
#define HD     128      // H == NF == 128
#define NCH    3        // virtual channels
#define BN     64       // nodes per block
#define EROWS  (BN*NCH) // 192 e-rows per block
#define ESTR   136      // 128 data + 8 pad cols; row stride 272B (16B aligned)
// Pad cols per row (row' = c*64+nl): [128..129]=fp32 dx, [130..131]=fp32 dy,
// [132..133]=fp32 dz, [134..135]=fp32 radial, OVERWRITTEN by fp32 s after
// epilogue-1 consumes radial (wave-private rows -> no race). This kills the
// separate s_s[] array: total LDS ~52.6 KB <= 53248 (52 KiB) so 3 blocks/CU
// fit even under a 4 KiB LDS allocation granule (r8 lesson: 53760 rounds to
// 56 KiB -> 3x56 > 160 KiB -> stuck at 2 blocks).
//
// e_buf row layout: row' = c*64 + nl (channel-major) -> every 16-row MFMA chunk
// is channel-pure; wave w owns chunks {w, w+4, w+8} = rows its epilogue-1 wrote
// -> GEMM1->2->3 need NO barriers.
// GEMM2/GEMM3 in two ct-halves (acc[3][4] = 48 AGPR live) -> combined
// VGPR+AGPR ~140 <= 170 -> 3 waves/SIMD. launch_bounds stays (256,2): budget
// floor only; any smaller budget makes the allocator split the file and spill
// (r3/r4/r7: ~GBs of scratch traffic).

typedef short short8 __attribute__((ext_vector_type(8)));
typedef float f32x4  __attribute__((ext_vector_type(4)));

#define MFMA_16x16x32(a,b,c) __builtin_amdgcn_mfma_f32_16x16x32_bf16((a),(b),(c),0,0,0)

__device__ __forceinline__ float bf2f(unsigned short u) {
    return __uint_as_float(((unsigned int)u) << 16);
}
// round-half-up: 2 VALU ops; ties measure-zero for arithmetic-derived floats.
__device__ __forceinline__ unsigned short f2bf(float f) {
    return (unsigned short)((__float_as_uint(f) + 0x8000u) >> 16);
}
__device__ __forceinline__ float silu_f(float x) {
    return x * __builtin_amdgcn_rcpf(1.0f + __expf(-x));
}

// ---------------------------------------------------------------------------
// prep: blocks [0,192) repack We1[0:128]/We2/Wc1 into bf16 MFMA B-frag order
//   rep[((ct*4+ks)*64 + lane)*8 + j] = bf16(W[ks*32+(lane>>4)*8+j][ct*16+(lane&15)])
// blocks [192,492) compute Q[b,c,h] = sum_k vnf[b,k,c]*We1[128+k,h]
// ---------------------------------------------------------------------------
__global__ void prep_kernel(const float* __restrict__ We1,
                            const float* __restrict__ We2,
                            const float* __restrict__ Wc1,
                            const float* __restrict__ be1,
                            const float* __restrict__ be2,
                            const float* __restrict__ bc1,
                            const float* __restrict__ Wc2,
                            const float* __restrict__ vnf,
                            unsigned short* __restrict__ w1r,
                            unsigned short* __restrict__ w2r,
                            unsigned short* __restrict__ wc1r,
                            float* __restrict__ Q,
                            float* __restrict__ wlast,
                            float* __restrict__ be1f,
                            float* __restrict__ be2f,
                            float* __restrict__ bc1f,
                            float* __restrict__ wc2f) {
    int bid = blockIdx.x;
    if (bid < 192) {
        int t = bid * 256 + threadIdx.x;   // < 49152 = 3*16384
        int m  = t / 16384;
        int e  = t % 16384;
        int j  = e & 7;
        int l  = (e >> 3) & 63;
        int ks = (e >> 9) & 3;
        int ct = e >> 11;
        int row = ks * 32 + (l >> 4) * 8 + j;
        int col = ct * 16 + (l & 15);
        const float*    src = (m == 0) ? We1 : ((m == 1) ? We2 : Wc1);
        unsigned short* dst = (m == 0) ? w1r : ((m == 1) ? w2r : wc1r);
        dst[e] = f2bf(src[row * 128 + col]);
        if (t < 128) {
            wlast[t] = We1[256 * 128 + t];
            be1f[t]  = be1[t];
            be2f[t]  = be2[t];
            bc1f[t]  = bc1[t];
            wc2f[t]  = Wc2[t];
        }
    } else {
        int bc = bid - 192;                // 0..299
        int b = bc / NCH, c = bc % NCH;
        int t = threadIdx.x;
        __shared__ float v[128];
        if (t < 128) v[t] = vnf[(b * 128 + t) * 3 + c];
        __syncthreads();
        if (t < 128) {
            float s = 0.0f;
            for (int k = 0; k < 128; ++k)
                s += v[k] * We1[(128 + k) * 128 + t];
            Q[(b * 3 + c) * 128 + t] = s;
        }
    }
}

// ---------------------------------------------------------------------------
// Main fused kernel: 64 nodes/block, 256 threads (4 waves), 3125 blocks.
// ---------------------------------------------------------------------------
__global__ __launch_bounds__(256, 2) void egcl_main(
    const float* __restrict__ node_feat,   // [N,128]
    const float* __restrict__ coord,       // [N,3]
    const float* __restrict__ vcoord,      // [B,3,C]
    const int*   __restrict__ batch,       // [N] sorted
    const unsigned short* __restrict__ w1r,
    const unsigned short* __restrict__ w2r,
    const unsigned short* __restrict__ wc1r,
    const float* __restrict__ Q,           // [B,C,H]
    const float* __restrict__ wlast,
    const float* __restrict__ be1f,
    const float* __restrict__ be2f,
    const float* __restrict__ bc1f,
    const float* __restrict__ wc2f,
    float* __restrict__ aggsum,            // [B,C,H]
    float* __restrict__ transsum,          // [B,3,C]
    float* __restrict__ cnt)               // [B]
{
    __shared__ __align__(16) unsigned short e_buf[EROWS * ESTR]; // 52224 B
    __shared__ unsigned short sbatch[BN];
    __shared__ unsigned short sseg_start[BN + 1];
    __shared__ unsigned short sseg_b[BN];
    __shared__ int snseg;

    const int tid   = threadIdx.x;
    const int wave  = tid >> 6;
    const int lane  = tid & 63;
    const int lrow  = lane & 15;           // MFMA row (A) / col (D) index
    const int lkb   = (lane >> 4) * 8;     // k-offset base within 32-wide K step
    const int rq    = (lane >> 4) * 4;     // D row-group base
    const int node0 = blockIdx.x * BN;

    // ---- Phase 0 ----
    if (tid < BN) {  // wave 0
        int n = node0 + tid;
        int b = batch[n];
        sbatch[tid] = (unsigned short)b;
        int prev = (tid > 0) ? batch[n - 1] : -1;
        unsigned long long mask = __ballot(b != prev);
        int ns = __popcll(mask);
        if (b != prev) {
            int idx = __popcll(mask & ((1ull << tid) - 1ull));
            sseg_start[idx] = (unsigned short)tid;
            sseg_b[idx]     = (unsigned short)b;
        }
        if (tid == 0) { sseg_start[ns] = BN; snseg = ns; }
        float cx = coord[n * 3 + 0];
        float cy = coord[n * 3 + 1];
        float cz = coord[n * 3 + 2];
        for (int c = 0; c < 3; ++c) {
            float dx = vcoord[b * 9 + 0 * 3 + c] - cx;
            float dy = vcoord[b * 9 + 1 * 3 + c] - cy;
            float dz = vcoord[b * 9 + 2 * 3 + c] - cz;
            f32x4 pad;
            pad[0] = dx; pad[1] = dy; pad[2] = dz;
            pad[3] = sqrtf(dx * dx + dy * dy + dz * dz);
            *(f32x4*)&e_buf[(c * 64 + tid) * ESTR + 128] = pad;  // 16B aligned
        }
    }
    __syncthreads();
    const int nseg = snseg;   // block-uniform

    // ---- GEMM1: P[64,128] = node_feat_tile @ We1_top; wave w -> nodes 16w..16w+15
    f32x4 acc1[8] = {};
    {
        const float* arow = node_feat + (size_t)(node0 + wave * 16 + lrow) * 128;
        for (int ks = 0; ks < 4; ++ks) {
            f32x4 x0 = *(const f32x4*)(arow + ks * 32 + lkb);
            f32x4 x1 = *(const f32x4*)(arow + ks * 32 + lkb + 4);
            short8 af;
            af[0] = (short)f2bf(x0[0]); af[1] = (short)f2bf(x0[1]);
            af[2] = (short)f2bf(x0[2]); af[3] = (short)f2bf(x0[3]);
            af[4] = (short)f2bf(x1[0]); af[5] = (short)f2bf(x1[1]);
            af[6] = (short)f2bf(x1[2]); af[7] = (short)f2bf(x1[3]);
            for (int ct = 0; ct < 8; ++ct) {
                short8 bfg = *(const short8*)(w1r + ((ct * 4 + ks) * 64 + lane) * 8);
                acc1[ct] = MFMA_16x16x32(af, bfg, acc1[ct]);
            }
        }
    }
    // Epilogue 1: E1[c*64+nl, h] = silu(P + Q[b,c,h] + radial*wlast[h] + be1[h])
    {
        float wl[8], bb[8];
        #pragma unroll
        for (int ct = 0; ct < 8; ++ct) {
            wl[ct] = wlast[ct * 16 + lrow];
            bb[ct] = be1f[ct * 16 + lrow];
        }
        if (nseg == 1) {
            const float* qb = Q + (int)sseg_b[0] * (NCH * HD);
            float qv[3][8];
            #pragma unroll
            for (int c = 0; c < 3; ++c)
                #pragma unroll
                for (int ct = 0; ct < 8; ++ct)
                    qv[c][ct] = qb[c * 128 + ct * 16 + lrow];
            #pragma unroll
            for (int r = 0; r < 4; ++r) {
                int nl = wave * 16 + rq + r;
                #pragma unroll
                for (int c = 0; c < 3; ++c) {
                    int row = c * 64 + nl;
                    float rad = *(const float*)&e_buf[row * ESTR + 134];
                    #pragma unroll
                    for (int ct = 0; ct < 8; ++ct) {
                        float x = acc1[ct][r] + bb[ct] + qv[c][ct] + rad * wl[ct];
                        e_buf[row * ESTR + ct * 16 + lrow] = f2bf(silu_f(x));
                    }
                }
            }
        } else {
            #pragma unroll
            for (int r = 0; r < 4; ++r) {
                int nl = wave * 16 + rq + r;
                int b  = sbatch[nl];
                #pragma unroll
                for (int c = 0; c < 3; ++c) {
                    int row = c * 64 + nl;
                    float rad = *(const float*)&e_buf[row * ESTR + 134];
                    const float* qb = Q + (b * 3 + c) * 128;
                    #pragma unroll
                    for (int ct = 0; ct < 8; ++ct) {
                        float x = acc1[ct][r] + bb[ct] + qb[ct * 16 + lrow] + rad * wl[ct];
                        e_buf[row * ESTR + ct * 16 + lrow] = f2bf(silu_f(x));
                    }
                }
            }
        }
    }
    // (no barrier: wave w's chunks {w, w+4, w+8} are exactly the rows it wrote;
    //  radial in pad col 134 is now dead for this wave's rows)

    const int bagg = (nseg == 1) ? (int)sseg_b[0] * (NCH * HD) : 0;

    // ---- GEMM2: M = silu(E1 @ We2 + be2), in two ct-halves (48 AGPR live) ----
    for (int half = 0; half < 2; ++half) {
        f32x4 acc[3][4] = {};
        for (int ks = 0; ks < 4; ++ks) {
            short8 af[3];
            #pragma unroll
            for (int j = 0; j < 3; ++j)
                af[j] = *(const short8*)(&e_buf[(j * 64 + wave * 16 + lrow) * ESTR +
                                                ks * 32 + lkb]);
            #pragma unroll
            for (int c4 = 0; c4 < 4; ++c4) {
                int ct = half * 4 + c4;
                short8 bfg = *(const short8*)(w2r + ((ct * 4 + ks) * 64 + lane) * 8);
                #pragma unroll
                for (int j = 0; j < 3; ++j)
                    acc[j][c4] = MFMA_16x16x32(af[j], bfg, acc[j][c4]);
            }
        }
        // Epilogue 2 (this half): write M (bf16) + fast-path segment-sum
        for (int j = 0; j < 3; ++j) {
            #pragma unroll
            for (int c4 = 0; c4 < 4; ++c4) {
                int ct = half * 4 + c4;
                int h = ct * 16 + lrow;
                float bb = be2f[h];
                float psum = 0.0f;
                #pragma unroll
                for (int r = 0; r < 4; ++r) {
                    int row = j * 64 + wave * 16 + rq + r;
                    float v = silu_f(acc[j][c4][r] + bb);
                    e_buf[row * ESTR + h] = f2bf(v);
                    psum += v;
                }
                if (nseg == 1) {
                    psum += __shfl_xor(psum, 16, 64);
                    psum += __shfl_xor(psum, 32, 64);
                    if (lane < 16)
                        atomicAdd(&aggsum[bagg + j * 128 + ct * 16 + lane], psum);
                }
            }
        }
    }

    // ---- GEMM3: SH = silu(M @ Wc1 + bc1); s = SH . Wc2, two ct-halves ----
    float p[3][4] = {};
    for (int half = 0; half < 2; ++half) {
        f32x4 acc[3][4] = {};
        for (int ks = 0; ks < 4; ++ks) {
            short8 af[3];
            #pragma unroll
            for (int j = 0; j < 3; ++j)
                af[j] = *(const short8*)(&e_buf[(j * 64 + wave * 16 + lrow) * ESTR +
                                                ks * 32 + lkb]);
            #pragma unroll
            for (int c4 = 0; c4 < 4; ++c4) {
                int ct = half * 4 + c4;
                short8 bfg = *(const short8*)(wc1r + ((ct * 4 + ks) * 64 + lane) * 8);
                #pragma unroll
                for (int j = 0; j < 3; ++j)
                    acc[j][c4] = MFMA_16x16x32(af[j], bfg, acc[j][c4]);
            }
        }
        for (int j = 0; j < 3; ++j) {
            #pragma unroll
            for (int c4 = 0; c4 < 4; ++c4) {
                int ct = half * 4 + c4;
                int h = ct * 16 + lrow;
                float bb = bc1f[h];
                float w2 = wc2f[h];
                #pragma unroll
                for (int r = 0; r < 4; ++r)
                    p[j][r] += silu_f(acc[j][c4][r] + bb) * w2;
            }
        }
    }
    for (int j = 0; j < 3; ++j) {
        float p0 = p[j][0], p1 = p[j][1], p2 = p[j][2], p3 = p[j][3];
        #pragma unroll
        for (int off = 1; off < 16; off <<= 1) {
            p0 += __shfl_xor(p0, off, 64);
            p1 += __shfl_xor(p1, off, 64);
            p2 += __shfl_xor(p2, off, 64);
            p3 += __shfl_xor(p3, off, 64);
        }
        if (lrow == 0) {   // s -> pad col 134 (old radial slot), wave-private rows
            int rbase = j * 64 + wave * 16 + rq;
            *(float*)&e_buf[(rbase + 0) * ESTR + 134] = p0;
            *(float*)&e_buf[(rbase + 1) * ESTR + 134] = p1;
            *(float*)&e_buf[(rbase + 2) * ESTR + 134] = p2;
            *(float*)&e_buf[(rbase + 3) * ESTR + 134] = p3;
        }
    }
    __syncthreads();

    // ---- Reduce to global (aggsum fast path already done in epilogue 2) ----
    if (nseg == 1) {
        int b = sseg_b[0];
        if (wave == 0) {   // trans: 64-lane shuffle tree over nodes
            float t[9];
            #pragma unroll
            for (int c = 0; c < 3; ++c) {
                int row = c * 64 + lane;
                float sv = *(const float*)&e_buf[row * ESTR + 134];
                float dx = *(const float*)&e_buf[row * ESTR + 128];
                float dy = *(const float*)&e_buf[row * ESTR + 130];
                float dz = *(const float*)&e_buf[row * ESTR + 132];
                t[0 * 3 + c] = dx * sv;
                t[1 * 3 + c] = dy * sv;
                t[2 * 3 + c] = dz * sv;
            }
            #pragma unroll
            for (int off = 1; off < 64; off <<= 1)
                #pragma unroll
                for (int k = 0; k < 9; ++k)
                    t[k] += __shfl_xor(t[k], off, 64);
            if (lane < 9)
                atomicAdd(&transsum[b * 9 + lane],
                          __shfl(t[lane], 0, 64));  // lane0 holds full sums
            if (lane == 0) atomicAdd(&cnt[b], 64.0f);
        }
    } else {
        for (int sg = 0; sg < nseg; ++sg) {
            int s0 = sseg_start[sg], s1 = sseg_start[sg + 1], b = sseg_b[sg];
            for (int idx = tid; idx < NCH * HD; idx += 256) {
                int c = idx >> 7, h = idx & 127;
                float sum = 0.f;
                for (int ii = s0; ii < s1; ++ii)
                    sum += bf2f(e_buf[(c * 64 + ii) * ESTR + h]);
                atomicAdd(&aggsum[(b * 3 + c) * 128 + h], sum);
            }
            if (tid < 9) {
                int d = tid / 3, c = tid % 3;
                float sum = 0.f;
                for (int ii = s0; ii < s1; ++ii)
                    sum += (*(const float*)&e_buf[(c * 64 + ii) * ESTR + 128 + 2 * d])
                           * (*(const float*)&e_buf[(c * 64 + ii) * ESTR + 134]);
                atomicAdd(&transsum[b * 9 + d * 3 + c], sum);
            }
            if (tid == 0) atomicAdd(&cnt[b], (float)(s1 - s0));
        }
    }
}

// ---------------------------------------------------------------------------
// Finalize: one block per (b,c) row. Means, node model, residuals, outputs.
// ---------------------------------------------------------------------------
__global__ void finalize_kernel(const float* __restrict__ vnf,
                                const float* __restrict__ vcoord,
                                const float* __restrict__ Wn1,
                                const float* __restrict__ bn1,
                                const float* __restrict__ Wn2,
                                const float* __restrict__ bn2,
                                const float* __restrict__ aggsum,
                                const float* __restrict__ transsum,
                                const float* __restrict__ cnt,
                                float* __restrict__ out) {
    int b = blockIdx.x / NCH;
    int c = blockIdx.x % NCH;
    int j = threadIdx.x;   // 0..127
    __shared__ float nin[256];
    __shared__ float h1[128];
    float count = fmaxf(cnt[b], 1.0f);
    nin[j]       = vnf[(b * 128 + j) * 3 + c];
    nin[128 + j] = aggsum[(b * 3 + c) * 128 + j] / count;
    __syncthreads();
    float x = bn1[j];
    for (int k = 0; k < 256; ++k)
        x += nin[k] * Wn1[k * 128 + j];
    h1[j] = silu_f(x);
    __syncthreads();
    float y = bn2[j];
    for (int k = 0; k < 128; ++k)
        y += h1[k] * Wn2[k * 128 + j];
    out[(b * 128 + j) * 3 + c] = vnf[(b * 128 + j) * 3 + c] + y;
    if (c == 0 && j < 9) {
        out[NGRAPH * 128 * 3 + b * 9 + j] =
            vcoord[b * 9 + j] + transsum[b * 9 + j] / count;
    }
}

// ---------------------------------------------------------------------------
extern "C" void kernel_launch(void* const* d_in, const int* in_sizes, int n_in,
                              void* d_out, int out_size, void* d_ws, size_t ws_size,
                              hipStream_t stream) {
    const float* node_feat = (const float*)d_in[0];
    const float* coord     = (const float*)d_in[1];
    const float* vnf       = (const float*)d_in[2];
    const float* vcoord    = (const float*)d_in[3];
    const int*   batch     = (const int*)d_in[4];
    const float* We1 = (const float*)d_in[5];
    const float* be1 = (const float*)d_in[6];
    const float* We2 = (const float*)d_in[7];
    const float* be2 = (const float*)d_in[8];
    const float* Wc1 = (const float*)d_in[9];
    const float* bc1 = (const float*)d_in[10];
    const float* Wc2 = (const float*)d_in[11];
    const float* Wn1 = (const float*)d_in[12];
    const float* bn1 = (const float*)d_in[13];
    const float* Wn2 = (const float*)d_in[14];
    const float* bn2 = (const float*)d_in[15];

    char* ws = (char*)d_ws;
    float*          aggsum   = (float*)(ws + 0);          // 153600
    float*          transsum = (float*)(ws + 153600);     // 3600
    float*          cntp     = (float*)(ws + 157200);     // 400
    float*          Q        = (float*)(ws + 157600);     // 153600
    unsigned short* w1r      = (unsigned short*)(ws + 311200); // 32768
    unsigned short* w2r      = (unsigned short*)(ws + 343968); // 32768
    unsigned short* wc1r     = (unsigned short*)(ws + 376736); // 32768
    float*          wlast    = (float*)(ws + 409504);
    float*          be1f     = (float*)(ws + 410016);
    float*          be2f     = (float*)(ws + 410528);
    float*          bc1f     = (float*)(ws + 411040);
    float*          wc2f     = (float*)(ws + 411552);

    (void)hipMemsetAsync(d_ws, 0, 157600, stream);  // zero accumulators each call

    prep_kernel<<<192 + NGRAPH * NCH, 256, 0, stream>>>(
        We1, We2, Wc1, be1, be2, bc1, Wc2, vnf,
        w1r, w2r, wc1r, Q, wlast, be1f, be2f, bc1f, wc2f);

    egcl_main<<<NNODES / BN, 256, 0, stream>>>(
        node_feat, coord, vcoord, batch, w1r, w2r, wc1r, Q,
        wlast, be1f, be2f, bc1f, wc2f, aggsum, transsum, cntp);

    finalize_kernel<<<NGRAPH * NCH, 128, 0, stream>>>(
        vnf, vcoord, Wn1, bn1, Wn2, bn2, aggsum, transsum, cntp,
        (float*)d_out);
}